// Round 5
// baseline (84.573 us; speedup 1.0000x reference)
//
#include <hip/hip_runtime.h>

#define H 1024
#define W 1024
#define NPIX (H * W)
#define WW 16          // 64-row words per column
#define INF_F 1e12f
#define THREADS 256
#define BIG (1 << 29)

// ---------------------------------------------------------------------------
// Exact vertical nearest-site distance for pixel (r,c), polarity pol
// (pol=1: sites are 1-pixels; pol=0: sites are 0-pixels). Cold path.
// ---------------------------------------------------------------------------
__device__ __noinline__ int vert_dist_full(const unsigned long long* __restrict__ pw,
                                           int r, int c, int pol) {
  int w = r >> 6, b = r & 63;
  unsigned long long v = pw[w * W + c];
  unsigned long long m_c = pol ? v : ~v;
  int dup = 1 << 30, ddn = 1 << 30;
  unsigned long long am = m_c & ((1ULL << b) - 1ULL);
  if (am) {
    dup = b - (63 - __builtin_clzll(am));
  } else {
    for (int ww = w - 1; ww >= 0; --ww) {
      unsigned long long mv = pw[ww * W + c];
      mv = pol ? mv : ~mv;
      if (mv) { dup = r - (ww * 64 + 63 - __builtin_clzll(mv)); break; }
    }
  }
  unsigned long long bm = m_c >> b;  // includes self
  if (bm) {
    ddn = __builtin_ctzll(bm);
  } else {
    for (int ww = w + 1; ww < WW; ++ww) {
      unsigned long long mv = pw[ww * W + c];
      mv = pol ? mv : ~mv;
      if (mv) { ddn = (ww * 64 + __builtin_ctzll(mv)) - r; break; }
    }
  }
  return min(dup, ddn);
}

// Cold exact continuation/restart of the parabola min. Never taken at p=0.5.
__device__ __noinline__ int horiz_exact(const unsigned long long* __restrict__ pw,
                                        int r, int c, int pol, int best, int dk0) {
  for (int dk = dk0; dk < W; ++dk) {
    int dk2 = dk * dk;
    if (dk2 >= best) break;
    if (c - dk >= 0) {
      int d = vert_dist_full(pw, r, c - dk, pol);
      if (d < H) best = min(best, d * d + dk2);
    }
    if (c + dk < W) {
      int d = vert_dist_full(pw, r, c + dk, pol);
      if (d < H) best = min(best, d * d + dk2);
    }
  }
  return best;
}

// ---------------------------------------------------------------------------
// Kernel A: pack target (0/1 int32) into a bit matrix, column-major bits:
// pw[w*W + c] bit b = (target[(w*64+b)*W + c] != 0). Stored as u32 halves.
// Also zeroes the done-counter (ws is re-poisoned 0xAA before every call).
// ---------------------------------------------------------------------------
__global__ __launch_bounds__(THREADS) void pack_bits(
    const int* __restrict__ target, unsigned int* __restrict__ pw32,
    unsigned int* __restrict__ counter) {
  if (blockIdx.x == 0 && threadIdx.x == 0) *counter = 0;
  int tg = blockIdx.x * THREADS + threadIdx.x;  // 32768 threads
  int w = tg >> 11;
  int half = (tg >> 10) & 1;
  int c = tg & (W - 1);
  int rbase = w * 64 + half * 32;
  unsigned int val = 0;
#pragma unroll
  for (int b = 0; b < 32; ++b) {
    if (target[(rbase + b) * W + c] != 0) val |= (1u << b);
  }
  pw32[((w * W + c) << 1) + half] = val;
}

// ---------------------------------------------------------------------------
// Kernel B: fused vertical EDT (bit ops) + horizontal parabola envelope (LDS
// bytes) + input*sd product + block reduction + last-block final reduction.
// One row per block (1024 blocks -> 4 blocks/CU, 16 waves/CU).
// partials are 128-B strided (one L2 line per block) so no two blocks dirty
// the same line; writer __threadfence() (release writeback) + device-scope
// atomic counter + reader __threadfence() (acquire inv) give cross-XCD
// visibility per guideline 16.
// ---------------------------------------------------------------------------
__global__ __launch_bounds__(THREADS) void fused_edt_row(
    const unsigned long long* __restrict__ pw,
    const float* __restrict__ input,
    double* __restrict__ partials,        // stride 16 doubles (128 B)
    unsigned int* __restrict__ counter,
    float* __restrict__ out) {
  // byte distances, [pol][32 + c]; 255 = "d >= 255" sentinel / border pad
  __shared__ unsigned char sd8[2][W + 64];
  __shared__ double smem[THREADS / 64];
  __shared__ int lastflag;
  const int tid = threadIdx.x;
  const int r = blockIdx.x;
  const int w = r >> 6, b = r & 63;  // wave-uniform
  const int c0 = tid << 2;           // 4 consecutive columns per thread

  // border init: 2 planes x 16 pad-u32 (8 left + 8 right)
  if (tid < 32) {
    int p = tid >> 4, q = tid & 15;
    ((unsigned int*)sd8)[p * 272 + (q < 8 ? q : 256 + q)] = 0xFFFFFFFFu;
  }

  // ---- phase 1: vertical distances for 4 cols, both polarities ----
  unsigned long long curv[4], prevv[4], nextv[4];
  *(ulonglong2*)&curv[0] = *(const ulonglong2*)(pw + w * W + c0);
  *(ulonglong2*)&curv[2] = *(const ulonglong2*)(pw + w * W + c0 + 2);
  const bool hp = (w > 0), hn = (w < WW - 1);
  if (hp) {
    *(ulonglong2*)&prevv[0] = *(const ulonglong2*)(pw + (w - 1) * W + c0);
    *(ulonglong2*)&prevv[2] = *(const ulonglong2*)(pw + (w - 1) * W + c0 + 2);
  } else prevv[0] = prevv[1] = prevv[2] = prevv[3] = 0ULL;
  if (hn) {
    *(ulonglong2*)&nextv[0] = *(const ulonglong2*)(pw + (w + 1) * W + c0);
    *(ulonglong2*)&nextv[2] = *(const ulonglong2*)(pw + (w + 1) * W + c0 + 2);
  } else nextv[0] = nextv[1] = nextv[2] = nextv[3] = 0ULL;

  unsigned char dloc[2][4];  // [pol][k]
#pragma unroll
  for (int pol = 0; pol < 2; ++pol) {
#pragma unroll
    for (int k = 0; k < 4; ++k) {
      unsigned long long m_c = pol ? curv[k] : ~curv[k];
      unsigned long long m_p = hp ? (pol ? prevv[k] : ~prevv[k]) : 0ULL;
      unsigned long long m_n = hn ? (pol ? nextv[k] : ~nextv[k]) : 0ULL;
      int d = 1 << 30;
      unsigned long long am = m_c & ((1ULL << b) - 1ULL);
      if (am) d = b - (63 - __builtin_clzll(am));
      else if (m_p) d = b + 1 + __builtin_clzll(m_p);
      unsigned long long bm = m_c >> b;  // includes self
      int dd = 1 << 30;
      if (bm) dd = __builtin_ctzll(bm);
      else if (m_n) dd = (64 - b) + __builtin_ctzll(m_n);
      d = min(d, dd);
      // in-window hits are exact; any d>64 re-resolved exactly (cold, ~2^-64)
      if (d > 64) d = vert_dist_full(pw, r, c0 + k, pol);
      dloc[pol][k] = (unsigned char)min(d, 255);
    }
  }
  // LDS store: pack 4 col-bytes -> one u32 per pol; conflict-free
#pragma unroll
  for (int pol = 0; pol < 2; ++pol) {
    unsigned int u = (unsigned int)dloc[pol][0] |
                     ((unsigned int)dloc[pol][1] << 8) |
                     ((unsigned int)dloc[pol][2] << 16) |
                     ((unsigned int)dloc[pol][3] << 24);
    *(unsigned int*)&sd8[pol][32 + c0] = u;
  }
  __syncthreads();

  // ---- phase 2: horizontal envelope + product ----
  double val = 0.0;
  const float4 iv = *(const float4*)(input + r * W + c0);
  const float ivk[4] = {iv.x, iv.y, iv.z, iv.w};
#pragma unroll
  for (int k = 0; k < 4; ++k) {
    const bool t = (dloc[1][k] == 0);  // nearest-one dist 0 <=> t=1
    const int pol = t ? 0 : 1;         // t uses g_t (nearest zero)
    const int own = dloc[pol][k];
    int best = (own == 255) ? BIG : own * own;
    const unsigned char* __restrict__ sg = &sd8[pol][32 + c0 + k];
    // dk=1,2 unconditionally (branchless; extra probes preserve exactness)
#pragma unroll
    for (int dk = 1; dk <= 2; ++dk) {
      int dl = sg[-dk], dr = sg[dk];
      int gl = (dl == 255) ? BIG : dl * dl;
      int gr = (dr == 255) ? BIG : dr * dr;
      best = min(best, min(gl, gr) + dk * dk);
    }
    for (int dk = 3; dk <= 32; ++dk) {
      int dk2 = dk * dk;
      if (dk2 >= best) break;
      int dl = sg[-dk], dr = sg[dk];
      int gl = (dl == 255) ? BIG : dl * dl;
      int gr = (dr == 255) ? BIG : dr * dr;
      best = min(best, min(gl, gr) + dk2);
    }
    if (best > 1089) {  // cold exact fallback (beyond halo / sentinel)
      int c = c0 + k;
      if (best > 65025) {  // 255-sentinel could have hidden a true min
        int ov = vert_dist_full(pw, r, c, pol);
        best = (ov < H) ? ov * ov : (1 << 30);
        best = horiz_exact(pw, r, c, pol, best, 1);
      } else {
        best = horiz_exact(pw, r, c, pol, best, 33);
      }
    }
    float bestf = (best >= BIG) ? INF_F : (float)best;
    float dist = sqrtf(bestf);
    float sd = t ? (1.0f - dist) : dist;
    val += (double)(ivk[k] * sd);
  }

  // ---- phase 3: block reduction -> padded partial ----
  for (int off = 32; off > 0; off >>= 1)
    val += __shfl_down(val, off, 64);
  int lane = tid & 63, wid = tid >> 6;
  if (lane == 0) smem[wid] = val;
  __syncthreads();
  if (tid == 0) {
    double s = smem[0] + smem[1] + smem[2] + smem[3];
    partials[(size_t)blockIdx.x * 16] = s;   // one 128-B line per block
    __threadfence();                          // release: write back to LLC
    unsigned int old = atomicAdd(counter, 1u);
    lastflag = (old == (unsigned)(H - 1));
  }
  __syncthreads();

  // ---- phase 4: last finished block reduces all partials -> out ----
  if (lastflag) {
    __threadfence();  // acquire: invalidate stale lines before reading
    double s = 0.0;
#pragma unroll
    for (int i = 0; i < H / THREADS; ++i)
      s += partials[(size_t)(tid + i * THREADS) * 16];
    for (int off = 32; off > 0; off >>= 1)
      s += __shfl_down(s, off, 64);
    if (lane == 0) smem[wid] = s;
    __syncthreads();
    if (tid == 0)
      out[0] = (float)((smem[0] + smem[1] + smem[2] + smem[3]) / (double)NPIX);
  }
}

extern "C" void kernel_launch(void* const* d_in, const int* in_sizes, int n_in,
                              void* d_out, int out_size, void* d_ws, size_t ws_size,
                              hipStream_t stream) {
  const float* input = (const float*)d_in[0];
  const int* target = (const int*)d_in[1];
  float* out = (float*)d_out;

  // ws layout: counter @0; partials[1024] 128-B strided @1KiB (128 KiB);
  // pw (128 KiB) @256KiB.
  unsigned int* counter = (unsigned int*)d_ws;
  double* partials = (double*)((char*)d_ws + 1024);
  unsigned long long* pw = (unsigned long long*)((char*)d_ws + 262144);

  pack_bits<<<128, THREADS, 0, stream>>>(target, (unsigned int*)pw, counter);
  fused_edt_row<<<H, THREADS, 0, stream>>>(pw, input, partials, counter, out);
}

// Round 6
// 67.601 us; speedup vs baseline: 1.2511x; 1.2511x over previous
//
#include <hip/hip_runtime.h>

#define H 1024
#define W 1024
#define NPIX (H * W)
#define WW 16          // 64-row words per column
#define INF_F 1e12f
#define THREADS 256
#define BIG (1 << 29)

// ---------------------------------------------------------------------------
// Exact vertical nearest-site distance for pixel (r,c), polarity pol
// (pol=1: sites are 1-pixels; pol=0: sites are 0-pixels). Cold path.
// ---------------------------------------------------------------------------
__device__ __noinline__ int vert_dist_full(const unsigned long long* __restrict__ pw,
                                           int r, int c, int pol) {
  int w = r >> 6, b = r & 63;
  unsigned long long v = pw[w * W + c];
  unsigned long long m_c = pol ? v : ~v;
  int dup = 1 << 30, ddn = 1 << 30;
  unsigned long long am = m_c & ((1ULL << b) - 1ULL);
  if (am) {
    dup = b - (63 - __builtin_clzll(am));
  } else {
    for (int ww = w - 1; ww >= 0; --ww) {
      unsigned long long mv = pw[ww * W + c];
      mv = pol ? mv : ~mv;
      if (mv) { dup = r - (ww * 64 + 63 - __builtin_clzll(mv)); break; }
    }
  }
  unsigned long long bm = m_c >> b;  // includes self
  if (bm) {
    ddn = __builtin_ctzll(bm);
  } else {
    for (int ww = w + 1; ww < WW; ++ww) {
      unsigned long long mv = pw[ww * W + c];
      mv = pol ? mv : ~mv;
      if (mv) { ddn = (ww * 64 + __builtin_ctzll(mv)) - r; break; }
    }
  }
  return min(dup, ddn);
}

// Cold exact continuation/restart of the parabola min. Never taken at p=0.5.
__device__ __noinline__ int horiz_exact(const unsigned long long* __restrict__ pw,
                                        int r, int c, int pol, int best, int dk0) {
  for (int dk = dk0; dk < W; ++dk) {
    int dk2 = dk * dk;
    if (dk2 >= best) break;
    if (c - dk >= 0) {
      int d = vert_dist_full(pw, r, c - dk, pol);
      if (d < H) best = min(best, d * d + dk2);
    }
    if (c + dk < W) {
      int d = vert_dist_full(pw, r, c + dk, pol);
      if (d < H) best = min(best, d * d + dk2);
    }
  }
  return best;
}

// ---------------------------------------------------------------------------
// Kernel A: pack target (0/1 int32) into a bit matrix, column-major bits:
// pw[w*W + c] bit b = (target[(w*64+b)*W + c] != 0). Stored as u32 halves.
// ---------------------------------------------------------------------------
__global__ __launch_bounds__(THREADS) void pack_bits(
    const int* __restrict__ target, unsigned int* __restrict__ pw32) {
  int tg = blockIdx.x * THREADS + threadIdx.x;  // 32768 threads
  int w = tg >> 11;
  int half = (tg >> 10) & 1;
  int c = tg & (W - 1);
  int rbase = w * 64 + half * 32;
  unsigned int val = 0;
#pragma unroll
  for (int b = 0; b < 32; ++b) {
    if (target[(rbase + b) * W + c] != 0) val |= (1u << b);
  }
  pw32[((w * W + c) << 1) + half] = val;
}

// ---------------------------------------------------------------------------
// Kernel B: fused vertical EDT (bit ops) + horizontal parabola envelope (LDS
// bytes) + input*sd product + per-block reduction. One row per block (1024
// blocks -> 4 blocks/CU, 16 waves/CU). No device fences/atomics: R5 measured
// per-block __threadfence + same-address atomics at +18 us vs a 2 us reduce
// kernel — keep the 3-kernel split.
// ---------------------------------------------------------------------------
__global__ __launch_bounds__(THREADS) void fused_edt_row(
    const unsigned long long* __restrict__ pw,
    const float* __restrict__ input,
    double* __restrict__ partials) {
  // byte distances, [pol][32 + c]; 255 = "d >= 255" sentinel / border pad
  __shared__ unsigned char sd8[2][W + 64];
  const int tid = threadIdx.x;
  const int r = blockIdx.x;
  const int w = r >> 6, b = r & 63;  // wave-uniform
  const int c0 = tid << 2;           // 4 consecutive columns per thread

  // phase 0: issue the input load FIRST — its latency hides under the
  // vertical bit-math below (compiler won't hoist it across the barrier).
  const float4 iv = *(const float4*)(input + r * W + c0);

  // border init: 2 planes x 16 pad-u32 (8 left + 8 right)
  if (tid < 32) {
    int p = tid >> 4, q = tid & 15;
    ((unsigned int*)sd8)[p * 272 + (q < 8 ? q : 256 + q)] = 0xFFFFFFFFu;
  }

  // ---- phase 1: vertical distances for 4 cols, both polarities ----
  unsigned long long curv[4], prevv[4], nextv[4];
  *(ulonglong2*)&curv[0] = *(const ulonglong2*)(pw + w * W + c0);
  *(ulonglong2*)&curv[2] = *(const ulonglong2*)(pw + w * W + c0 + 2);
  const bool hp = (w > 0), hn = (w < WW - 1);
  if (hp) {
    *(ulonglong2*)&prevv[0] = *(const ulonglong2*)(pw + (w - 1) * W + c0);
    *(ulonglong2*)&prevv[2] = *(const ulonglong2*)(pw + (w - 1) * W + c0 + 2);
  } else prevv[0] = prevv[1] = prevv[2] = prevv[3] = 0ULL;
  if (hn) {
    *(ulonglong2*)&nextv[0] = *(const ulonglong2*)(pw + (w + 1) * W + c0);
    *(ulonglong2*)&nextv[2] = *(const ulonglong2*)(pw + (w + 1) * W + c0 + 2);
  } else nextv[0] = nextv[1] = nextv[2] = nextv[3] = 0ULL;

  unsigned char dloc[2][4];  // [pol][k]
#pragma unroll
  for (int pol = 0; pol < 2; ++pol) {
#pragma unroll
    for (int k = 0; k < 4; ++k) {
      unsigned long long m_c = pol ? curv[k] : ~curv[k];
      unsigned long long m_p = hp ? (pol ? prevv[k] : ~prevv[k]) : 0ULL;
      unsigned long long m_n = hn ? (pol ? nextv[k] : ~nextv[k]) : 0ULL;
      int d = 1 << 30;
      unsigned long long am = m_c & ((1ULL << b) - 1ULL);
      if (am) d = b - (63 - __builtin_clzll(am));
      else if (m_p) d = b + 1 + __builtin_clzll(m_p);
      unsigned long long bm = m_c >> b;  // includes self
      int dd = 1 << 30;
      if (bm) dd = __builtin_ctzll(bm);
      else if (m_n) dd = (64 - b) + __builtin_ctzll(m_n);
      d = min(d, dd);
      // in-window hits are exact; any d>64 re-resolved exactly (cold, ~2^-64)
      if (d > 64) d = vert_dist_full(pw, r, c0 + k, pol);
      dloc[pol][k] = (unsigned char)min(d, 255);
    }
  }
  // LDS store: pack 4 col-bytes -> one u32 per pol; conflict-free
#pragma unroll
  for (int pol = 0; pol < 2; ++pol) {
    unsigned int u = (unsigned int)dloc[pol][0] |
                     ((unsigned int)dloc[pol][1] << 8) |
                     ((unsigned int)dloc[pol][2] << 16) |
                     ((unsigned int)dloc[pol][3] << 24);
    *(unsigned int*)&sd8[pol][32 + c0] = u;
  }
  __syncthreads();

  // ---- phase 2: horizontal envelope + product ----
  double val = 0.0;
  const float ivk[4] = {iv.x, iv.y, iv.z, iv.w};
#pragma unroll
  for (int k = 0; k < 4; ++k) {
    const bool t = (dloc[1][k] == 0);  // nearest-one dist 0 <=> t=1
    const int pol = t ? 0 : 1;         // t uses g_t (nearest zero)
    const int own = dloc[pol][k];
    int best = (own == 255) ? BIG : own * own;
    const unsigned char* __restrict__ sg = &sd8[pol][32 + c0 + k];
    // dk=1,2 unconditionally (branchless; extra probes preserve exactness)
#pragma unroll
    for (int dk = 1; dk <= 2; ++dk) {
      int dl = sg[-dk], dr = sg[dk];
      int gl = (dl == 255) ? BIG : dl * dl;
      int gr = (dr == 255) ? BIG : dr * dr;
      best = min(best, min(gl, gr) + dk * dk);
    }
    for (int dk = 3; dk <= 32; ++dk) {
      int dk2 = dk * dk;
      if (dk2 >= best) break;
      int dl = sg[-dk], dr = sg[dk];
      int gl = (dl == 255) ? BIG : dl * dl;
      int gr = (dr == 255) ? BIG : dr * dr;
      best = min(best, min(gl, gr) + dk2);
    }
    if (best > 1089) {  // cold exact fallback (beyond halo / sentinel)
      int c = c0 + k;
      if (best > 65025) {  // 255-sentinel could have hidden a true min
        int ov = vert_dist_full(pw, r, c, pol);
        best = (ov < H) ? ov * ov : (1 << 30);
        best = horiz_exact(pw, r, c, pol, best, 1);
      } else {
        best = horiz_exact(pw, r, c, pol, best, 33);
      }
    }
    float bestf = (best >= BIG) ? INF_F : (float)best;
    float dist = sqrtf(bestf);
    float sd = t ? (1.0f - dist) : dist;
    val += (double)(ivk[k] * sd);
  }

  // ---- phase 3: block reduction ----
  for (int off = 32; off > 0; off >>= 1)
    val += __shfl_down(val, off, 64);
  __shared__ double smem[THREADS / 64];
  int lane = tid & 63, wid = tid >> 6;
  if (lane == 0) smem[wid] = val;
  __syncthreads();
  if (tid == 0)
    partials[blockIdx.x] = smem[0] + smem[1] + smem[2] + smem[3];
}

// ---------------------------------------------------------------------------
// Kernel C: reduce 1024 partials -> mean scalar. One 1024-thread block.
// ---------------------------------------------------------------------------
__global__ __launch_bounds__(1024) void reduce_partials(
    const double* __restrict__ partials, float* __restrict__ out) {
  double s = partials[threadIdx.x];
  for (int off = 32; off > 0; off >>= 1)
    s += __shfl_down(s, off, 64);
  __shared__ double smem[16];
  int lane = threadIdx.x & 63, wid = threadIdx.x >> 6;
  if (lane == 0) smem[wid] = s;
  __syncthreads();
  if (threadIdx.x == 0) {
    double t = 0.0;
#pragma unroll
    for (int i = 0; i < 16; ++i) t += smem[i];
    out[0] = (float)(t / (double)NPIX);
  }
}

extern "C" void kernel_launch(void* const* d_in, const int* in_sizes, int n_in,
                              void* d_out, int out_size, void* d_ws, size_t ws_size,
                              hipStream_t stream) {
  const float* input = (const float*)d_in[0];
  const int* target = (const int*)d_in[1];
  float* out = (float*)d_out;

  // workspace: [0,8KiB) partials[1024]; pw (128 KiB) at +8KiB
  double* partials = (double*)d_ws;
  unsigned long long* pw = (unsigned long long*)((char*)d_ws + 8192);

  pack_bits<<<128, THREADS, 0, stream>>>(target, (unsigned int*)pw);
  fused_edt_row<<<H, THREADS, 0, stream>>>(pw, input, partials);
  reduce_partials<<<1, 1024, 0, stream>>>(partials, out);
}